// Round 6
// baseline (219.891 us; speedup 1.0000x reference)
//
#include <hip/hip_runtime.h>

#define T_STEPS 2000
#define BATCH   2048

// Force a value to live in a VGPR (defeats compiler's SGPR-residency choice,
// which otherwise costs a v_mov broadcast per use since VALU ops allow only
// one SGPR operand).
#define FORCE_VGPR(x) asm("" : "+v"(x))

// Fully fused conv + recurrence, one rotating-ring wave per batch element.
//
// Ring invariant (entering step t): lane L holds
//   R_L = cba + sum_{tau<=t-1} (a[63-(t+L-tau)]/mc)*c_tau + gamma-weighted f's
// Per step t:
//   1. R += af * c_t            (af[L]=a[63-L]/mc; lane 0 becomes u_t)
//   2. u = readlane(R,0); f = relu(M*tanh(poly(u)))  (overflow-free form)
//   3. rotate R down one lane (DPP wave_rol:1), lane 63 <- cba (fresh slot)
//   4. R += gam * f             (gam[L]=(1000/mc)*b_lag[63-L], fixed)
//   5. F = cndmask(rotl1(F), f, lane63)   (output collector: after 64 steps
//      lane L holds f[t0+L]; shares the loop-invariant lane==63 mask with 3.)
__global__ __launch_bounds__(256) void fused_kernel(
    const float* __restrict__ currents, const float* __restrict__ a,
    const float* __restrict__ b_lag, const float* __restrict__ poly_coeff,
    const float* __restrict__ b_act, const float* __restrict__ max_current,
    const float* __restrict__ max_firing_rate, float* __restrict__ out)
{
    int tid  = threadIdx.x;
    int lane = tid & 63;
    int wid  = tid >> 6;
    int b    = blockIdx.x * 4 + wid;

    float inv = 1.0f / max_current[0];
    float cba = -b_act[0] * inv;
    float af  = a[63 - lane] * inv;                 // per-lane conv tap
    float gam = (1000.0f * inv) * b_lag[63 - lane]; // per-lane feedback tap

    // tanh(p) = 1 - 2/(exp2(K2*p)+1); K2 = 2*log2(e) folded into squared coeffs.
    const float K2 = 2.8853900817779268f;
    float c0 = poly_coeff[0], c1 = poly_coeff[1], c2 = poly_coeff[2], c3 = poly_coeff[3];
    float k0 = K2 * c0 * c0, k1 = K2 * c1 * c1, k2 = K2 * c2 * c2, k3 = K2 * c3 * c3;
    float M  = max_firing_rate[0];
    float m2 = -2.0f * M;

    // keep every per-step operand in VGPRs -> no v_mov broadcasts in the loop
    FORCE_VGPR(cba); FORCE_VGPR(af); FORCE_VGPR(gam);
    FORCE_VGPR(k0);  FORCE_VGPR(k1); FORCE_VGPR(k2); FORCE_VGPR(k3);
    FORCE_VGPR(M);   FORCE_VGPR(m2);

    auto bcast = [](float v, int l) {
        return __builtin_bit_cast(float,
            __builtin_amdgcn_readlane(__builtin_bit_cast(int, v), l));
    };
    auto rotl1 = [](float v) {   // dst[L] = src[(L+1) & 63]
        int i = __builtin_bit_cast(int, v);
        return __builtin_bit_cast(float,
            __builtin_amdgcn_update_dpp(i, i, 0x134, 0xf, 0xf, false));
    };

    const float* ccol   = currents + b;
    float*       outcol = out + b;

    bool  is63 = (lane == 63);               // loop-invariant cndmask predicate
    float R  = cba;                          // all slots born with the bias
    float cv = ccol[(long)lane * BATCH];     // c[lane] for chunk 0
    float F  = 0.0f;                         // output collector

    auto step = [&](int s) {
        float c = bcast(cv, s);                       // c_t -> SGPR
        R = fmaf(af, c, R);                           // v_fmac (1 SGPR src)
        float u = bcast(R, 0);                        // u_t -> SGPR
        FORCE_VGPR(u);                                // single mov, then VGPR math
        float u2 = u * u;                             // Estrin, depth 2
        float a1 = fmaf(u, k1, k0);
        float a2 = fmaf(u, k3, k2);
        float p  = fmaf(u2, a2, a1);
        float e  = __builtin_amdgcn_exp2f(p);
        float r  = __builtin_amdgcn_rcpf(e + 1.0f);
        float f  = fmaxf(fmaf(m2, r, M), 0.0f);       // relu(M*tanh), overflow-free
        float Rr = rotl1(R);                          // slots shift down one lane
        Rr = is63 ? cba : Rr;                         // fresh slot for t+64
        R  = fmaf(gam, f, Rr);
        float Fr = rotl1(F);                          // collect f in rotating reg
        F  = is63 ? f : Fr;
        (void)s;
    };

    // 31 full chunks of 64 steps (t = 0 .. 1983)
    for (int chunk = 0; chunk < 31; ++chunk) {
        int t0 = chunk * 64;
        int tp = t0 + 64 + lane;                      // prefetch next chunk's currents
        float cv_next = (tp < T_STEPS) ? ccol[(long)tp * BATCH] : 0.0f;
#pragma unroll
        for (int s = 0; s < 64; ++s) step(s);
        outcol[(long)(t0 + lane) * BATCH] = F;        // lane L = f[t0+L]
        cv = cv_next;
    }
    // tail: 16 steps (t = 1984 .. 1999); f[1984+s] ends at lane 48+s
#pragma unroll
    for (int s = 0; s < 16; ++s) step(s);
    if (lane >= 48) outcol[(long)(1984 + lane - 48) * BATCH] = F;
}

extern "C" void kernel_launch(void* const* d_in, const int* in_sizes, int n_in,
                              void* d_out, int out_size, void* d_ws, size_t ws_size,
                              hipStream_t stream) {
    const float* currents   = (const float*)d_in[0];
    const float* a          = (const float*)d_in[1];
    const float* b_lag      = (const float*)d_in[2];
    const float* poly_coeff = (const float*)d_in[3];
    const float* b_act      = (const float*)d_in[4];
    const float* mc         = (const float*)d_in[5];
    const float* mfr        = (const float*)d_in[6];
    float* out = (float*)d_out;

    fused_kernel<<<BATCH / 4, 256, 0, stream>>>(
        currents, a, b_lag, poly_coeff, b_act, mc, mfr, out);
}